// Round 6
// baseline (9564.927 us; speedup 1.0000x reference)
//
#include <hip/hip_runtime.h>
#include <math.h>

#define TWOPI_F 6.283185307179586f
#define LD4(p) (*(const float4*)(p))

__device__ __forceinline__ float gelu_f(float v) {
    float u = 0.7978845608028654f * (v + 0.044715f * v * v * v);
    return 0.5f * v * (1.f + tanhf(u));
}

// ---------------- twiddle tables ----------------
__global__ void init_tables_kernel(float* __restrict__ Wy, float* __restrict__ TWX,
                                   float* __restrict__ WY2) {
    int t = threadIdx.x;
    for (int i = t; i < 1024; i += 256) {
        int y = i >> 4, k = i & 15;
        int m = (k * y) & 63;
        float a = -TWOPI_F * (float)m / 64.f;
        Wy[y * 32 + 2 * k]     = cosf(a);
        Wy[y * 32 + 2 * k + 1] = sinf(a);
    }
    for (int i = t; i < 2048; i += 256) {
        int x = i >> 5, kxm = i & 31;
        int kx = kxm < 16 ? kxm : kxm + 32;
        int m = (kx * x) & 63;
        float a = -TWOPI_F * (float)m / 64.f;
        TWX[x * 64 + 2 * kxm]     = cosf(a);
        TWX[x * 64 + 2 * kxm + 1] = sinf(a);
    }
    for (int i = t; i < 1024; i += 256) {
        int y = i >> 4, k = i & 15;
        int m = (k * y) & 63;
        float a = TWOPI_F * (float)m / 64.f;
        float sc = (k == 0 ? 1.f : 2.f) / 4096.f;
        WY2[y * 32 + 2 * k]     = sc * cosf(a);
        WY2[y * 32 + 2 * k + 1] = sc * sinf(a);
    }
}

// ---------------- router v3: weight-reuse layout (col-group x row-group) ----------------
__global__ __launch_bounds__(512) void router_kernel(
    const float* __restrict__ x, const float* __restrict__ enc_w, const float* __restrict__ enc_b,
    const float* __restrict__ wqkv, const float* __restrict__ bqkv,
    const float* __restrict__ wo, const float* __restrict__ bo,
    const float* __restrict__ ln1g, const float* __restrict__ ln1b,
    const float* __restrict__ w1, const float* __restrict__ b1,
    const float* __restrict__ w2, const float* __restrict__ b2,
    const float* __restrict__ ln2g, const float* __restrict__ ln2b,
    const float* __restrict__ fcw, const float* __restrict__ fcb,
    float* __restrict__ rw)
{
    __shared__ float s[64][65];
    __shared__ float qk[64][193];
    __shared__ float sc[64][65];
    __shared__ float o64[64][65];
    __shared__ float feat[64];
    __shared__ float logits[8];
    int b = blockIdx.x, t = threadIdx.x;

    for (int i = t; i < 4096; i += 512) {
        int w_ = i >> 6, d = i & 63;
        s[w_][d] = x[b * 4096 + w_] * enc_w[d] + enc_b[d];
    }
    __syncthreads();

    for (int l = 0; l < 2; ++l) {
        // ---- QKV: 48 col4-groups x 8 row-groups (384 active threads, 8 rows each)
        {
            const float* Wq = wqkv + l * 64 * 192;
            const float* Bq = bqkv + l * 192;
            int c4 = t % 48, rg = t / 48;
            if (rg < 8) {
                const float* wcol = Wq + 4 * c4;
                float4 bq = LD4(Bq + 4 * c4);
                float4 acc[8];
#pragma unroll
                for (int i = 0; i < 8; ++i) acc[i] = bq;
                int r0 = rg * 8;
#pragma unroll 8
                for (int k = 0; k < 64; ++k) {
                    float4 wv = LD4(wcol + k * 192);
#pragma unroll
                    for (int i = 0; i < 8; ++i) {
                        float sv = s[r0 + i][k];
                        acc[i].x += sv * wv.x; acc[i].y += sv * wv.y;
                        acc[i].z += sv * wv.z; acc[i].w += sv * wv.w;
                    }
                }
#pragma unroll
                for (int i = 0; i < 8; ++i) {
                    qk[r0 + i][4 * c4]     = acc[i].x;
                    qk[r0 + i][4 * c4 + 1] = acc[i].y;
                    qk[r0 + i][4 * c4 + 2] = acc[i].z;
                    qk[r0 + i][4 * c4 + 3] = acc[i].w;
                }
            }
        }
        __syncthreads();
        // ---- attention heads
        for (int h = 0; h < 4; ++h) {
            for (int i = t; i < 4096; i += 512) {
                int q = i >> 6, kj = i & 63;
                float acc = 0.f;
#pragma unroll
                for (int d = 0; d < 16; ++d)
                    acc += qk[q][h * 16 + d] * qk[kj][64 + h * 16 + d];
                sc[q][kj] = acc * 0.25f;
            }
            __syncthreads();
            if (t < 64) {
                float m = -1e30f;
                for (int j = 0; j < 64; ++j) m = fmaxf(m, sc[t][j]);
                float sum = 0.f;
                for (int j = 0; j < 64; ++j) { float e2 = expf(sc[t][j] - m); sc[t][j] = e2; sum += e2; }
                float inv = 1.f / sum;
                for (int j = 0; j < 64; ++j) sc[t][j] *= inv;
            }
            __syncthreads();
            for (int i = t; i < 1024; i += 512) {
                int q = i >> 4, d = i & 15;
                float acc = 0.f;
#pragma unroll 8
                for (int j = 0; j < 64; ++j) acc += sc[q][j] * qk[j][128 + h * 16 + d];
                o64[q][h * 16 + d] = acc;
            }
            __syncthreads();
        }
        // ---- attn out proj + residual: 16 col4 x 32 rg (2 rows each)
        {
            const float* Wo = wo + l * 4096;
            const float* Bo = bo + l * 64;
            int c4 = t & 15, rg = t >> 4;
            const float* wcol = Wo + 4 * c4;
            float4 acc0 = LD4(Bo + 4 * c4), acc1 = acc0;
            int r0 = rg * 2;
#pragma unroll 8
            for (int k = 0; k < 64; ++k) {
                float4 wv = LD4(wcol + k * 64);
                float h0 = o64[r0][k], h1 = o64[r0 + 1][k];
                acc0.x += h0 * wv.x; acc0.y += h0 * wv.y;
                acc0.z += h0 * wv.z; acc0.w += h0 * wv.w;
                acc1.x += h1 * wv.x; acc1.y += h1 * wv.y;
                acc1.z += h1 * wv.z; acc1.w += h1 * wv.w;
            }
            sc[r0][4 * c4]     = s[r0][4 * c4]     + acc0.x;
            sc[r0][4 * c4 + 1] = s[r0][4 * c4 + 1] + acc0.y;
            sc[r0][4 * c4 + 2] = s[r0][4 * c4 + 2] + acc0.z;
            sc[r0][4 * c4 + 3] = s[r0][4 * c4 + 3] + acc0.w;
            sc[r0 + 1][4 * c4]     = s[r0 + 1][4 * c4]     + acc1.x;
            sc[r0 + 1][4 * c4 + 1] = s[r0 + 1][4 * c4 + 1] + acc1.y;
            sc[r0 + 1][4 * c4 + 2] = s[r0 + 1][4 * c4 + 2] + acc1.z;
            sc[r0 + 1][4 * c4 + 3] = s[r0 + 1][4 * c4 + 3] + acc1.w;
        }
        __syncthreads();
        if (t < 64) {  // LN1: sc -> s
            float m = 0.f;
            for (int j = 0; j < 64; ++j) m += sc[t][j];
            m *= (1.f / 64.f);
            float v = 0.f;
            for (int j = 0; j < 64; ++j) { float d = sc[t][j] - m; v += d * d; }
            v *= (1.f / 64.f);
            float inv = rsqrtf(v + 1e-5f);
            for (int j = 0; j < 64; ++j)
                s[t][j] = (sc[t][j] - m) * inv * ln1g[l * 64 + j] + ln1b[l * 64 + j];
        }
        __syncthreads();
        // ---- FFN1 + relu: 64 col4 x 8 rg (8 rows each); out split qk/o64
        {
            const float* W1 = w1 + l * 64 * 256;
            const float* B1 = b1 + l * 256;
            int c4 = t & 63, rg = t >> 6;
            const float* wcol = W1 + 4 * c4;
            float4 b1v = LD4(B1 + 4 * c4);
            float4 acc[8];
#pragma unroll
            for (int i = 0; i < 8; ++i) acc[i] = b1v;
            int r0 = rg * 8;
#pragma unroll 4
            for (int k = 0; k < 64; ++k) {
                float4 wv = LD4(wcol + k * 256);
#pragma unroll
                for (int i = 0; i < 8; ++i) {
                    float sv = s[r0 + i][k];
                    acc[i].x += sv * wv.x; acc[i].y += sv * wv.y;
                    acc[i].z += sv * wv.z; acc[i].w += sv * wv.w;
                }
            }
#pragma unroll
            for (int i = 0; i < 8; ++i) {
                float a0 = fmaxf(acc[i].x, 0.f), a1 = fmaxf(acc[i].y, 0.f);
                float a2 = fmaxf(acc[i].z, 0.f), a3 = fmaxf(acc[i].w, 0.f);
                if (c4 < 48) {
                    qk[r0 + i][4 * c4] = a0; qk[r0 + i][4 * c4 + 1] = a1;
                    qk[r0 + i][4 * c4 + 2] = a2; qk[r0 + i][4 * c4 + 3] = a3;
                } else {
                    int c = 4 * c4 - 192;
                    o64[r0 + i][c] = a0; o64[r0 + i][c + 1] = a1;
                    o64[r0 + i][c + 2] = a2; o64[r0 + i][c + 3] = a3;
                }
            }
        }
        __syncthreads();
        // ---- FFN2 + residual: 16 col4 x 32 rg (2 rows each), K=256
        {
            const float* W2 = w2 + l * 256 * 64;
            const float* B2 = b2 + l * 64;
            int c4 = t & 15, rg = t >> 4;
            const float* wcol = W2 + 4 * c4;
            float4 acc0 = LD4(B2 + 4 * c4), acc1 = acc0;
            int r0 = rg * 2;
#pragma unroll 8
            for (int k = 0; k < 192; ++k) {
                float4 wv = LD4(wcol + k * 64);
                float h0 = qk[r0][k], h1 = qk[r0 + 1][k];
                acc0.x += h0 * wv.x; acc0.y += h0 * wv.y;
                acc0.z += h0 * wv.z; acc0.w += h0 * wv.w;
                acc1.x += h1 * wv.x; acc1.y += h1 * wv.y;
                acc1.z += h1 * wv.z; acc1.w += h1 * wv.w;
            }
#pragma unroll 8
            for (int k = 192; k < 256; ++k) {
                float4 wv = LD4(wcol + k * 64);
                float h0 = o64[r0][k - 192], h1 = o64[r0 + 1][k - 192];
                acc0.x += h0 * wv.x; acc0.y += h0 * wv.y;
                acc0.z += h0 * wv.z; acc0.w += h0 * wv.w;
                acc1.x += h1 * wv.x; acc1.y += h1 * wv.y;
                acc1.z += h1 * wv.z; acc1.w += h1 * wv.w;
            }
            sc[r0][4 * c4]     = s[r0][4 * c4]     + acc0.x;
            sc[r0][4 * c4 + 1] = s[r0][4 * c4 + 1] + acc0.y;
            sc[r0][4 * c4 + 2] = s[r0][4 * c4 + 2] + acc0.z;
            sc[r0][4 * c4 + 3] = s[r0][4 * c4 + 3] + acc0.w;
            sc[r0 + 1][4 * c4]     = s[r0 + 1][4 * c4]     + acc1.x;
            sc[r0 + 1][4 * c4 + 1] = s[r0 + 1][4 * c4 + 1] + acc1.y;
            sc[r0 + 1][4 * c4 + 2] = s[r0 + 1][4 * c4 + 2] + acc1.z;
            sc[r0 + 1][4 * c4 + 3] = s[r0 + 1][4 * c4 + 3] + acc1.w;
        }
        __syncthreads();
        if (t < 64) {  // LN2: sc -> s
            float m = 0.f;
            for (int j = 0; j < 64; ++j) m += sc[t][j];
            m *= (1.f / 64.f);
            float v = 0.f;
            for (int j = 0; j < 64; ++j) { float d = sc[t][j] - m; v += d * d; }
            v *= (1.f / 64.f);
            float inv = rsqrtf(v + 1e-5f);
            for (int j = 0; j < 64; ++j)
                s[t][j] = (sc[t][j] - m) * inv * ln2g[l * 64 + j] + ln2b[l * 64 + j];
        }
        __syncthreads();
    }
    if (t < 64) {
        float m = -1e30f;
        for (int r = 0; r < 64; ++r) m = fmaxf(m, s[r][t]);
        feat[t] = m;
    }
    __syncthreads();
    if (t < 8) {
        float acc = fcb[t];
        for (int k = 0; k < 64; ++k) acc += feat[k] * fcw[k * 8 + t];
        logits[t] = acc;
    }
    __syncthreads();
    if (t == 0) {
        int i0 = 0;
        for (int j = 1; j < 8; ++j) if (logits[j] > logits[i0]) i0 = j;
        int i1 = -1;
        for (int j = 0; j < 8; ++j) {
            if (j == i0) continue;
            if (i1 < 0 || logits[j] > logits[i1]) i1 = j;
        }
        float e1 = expf(logits[i1] - logits[i0]);
        float w0 = 1.f / (1.f + e1);
        float w1v = e1 / (1.f + e1);
        for (int j = 0; j < 8; ++j) rw[b * 8 + j] = 0.f;
        rw[b * 8 + i0] = w0;
        rw[b * 8 + i1] = w1v;
    }
}

// ---------------- build compact (b,e) pair list grouped by expert ----------------
__global__ void build_pairs_kernel(const float* __restrict__ rw, int* __restrict__ pair_b,
                                   int* __restrict__ pair_e, float* __restrict__ pair_w,
                                   int* __restrict__ estart) {
    __shared__ float r[256];
    __shared__ int cnt[8], off[9];
    int t = threadIdx.x;
    for (int i = t; i < 256; i += 64) r[i] = rw[i];
    if (t < 64) { pair_b[t] = 0; pair_e[t] = 0; pair_w[t] = 0.f; }
    __syncthreads();
    if (t < 8) {
        int c = 0;
        for (int b = 0; b < 32; ++b) if (r[b * 8 + t] != 0.f) ++c;
        cnt[t] = c;
    }
    __syncthreads();
    if (t == 0) {
        int a = 0;
        for (int e = 0; e < 8; ++e) { off[e] = a; a += cnt[e]; }
        off[8] = a;
        for (int e = 0; e <= 8; ++e) estart[e] = off[e];
    }
    __syncthreads();
    if (t < 8) {
        int n = off[t];
        for (int b = 0; b < 32; ++b) {
            float w = r[b * 8 + t];
            if (w != 0.f) { pair_b[n] = b; pair_e[n] = t; pair_w[n] = w; ++n; }
        }
    }
}

// ---------------- lift ----------------
__global__ __launch_bounds__(256) void lift_kernel(const float* __restrict__ x,
    const float* __restrict__ lw, const float* __restrict__ lb,
    const int* __restrict__ pair_b, const int* __restrict__ pair_e, float* __restrict__ hA) {
    int p = blockIdx.x, tile = blockIdx.y, t = threadIdx.x;
    int b = pair_b[p], e = pair_e[p];
    float* h = hA + (size_t)p * 262144;
    const float* xb = x + (size_t)b * 4096;
    for (int i = tile * 16384 + t; i < (tile + 1) * 16384; i += 256) {
        int co = i >> 12, xy = i & 4095;
        h[i] = xb[xy] * lw[e * 64 + co] + lb[e * 64 + co];
    }
}

// ---------------- fused forward DFT (y then x), one block per (p,ci) ----------------
__global__ __launch_bounds__(256) void fwdft_kernel(const float* __restrict__ h,
    const float* __restrict__ Wy, const float* __restrict__ TWX, float* __restrict__ F) {
    __shared__ float ht[64][68];
    __shared__ float gt[64][36];
    __shared__ float wy[2048];
    __shared__ float twx[4096];
    int bid = blockIdx.x;
    int t = threadIdx.x;
    const float* src = h + (size_t)bid * 4096;
    for (int i = t; i < 1024; i += 256) {
        float4 v = *(const float4*)(src + i * 4);
        int x = (i * 4) >> 6, y = (i * 4) & 63;
        *(float4*)(&ht[x][y]) = v;
    }
    for (int i = t; i < 512; i += 256) *(float4*)(&wy[i * 4]) = *(const float4*)(Wy + i * 4);
    for (int i = t; i < 1024; i += 256) *(float4*)(&twx[i * 4]) = *(const float4*)(TWX + i * 4);
    __syncthreads();
    {
        int xx = t >> 2, kq = t & 3;
        float gr0 = 0.f, gi0 = 0.f, gr1 = 0.f, gi1 = 0.f;
        float gr2 = 0.f, gi2 = 0.f, gr3 = 0.f, gi3 = 0.f;
#pragma unroll 4
        for (int y = 0; y < 64; ++y) {
            float hv = ht[xx][y];
            float4 w0 = *(const float4*)(&wy[y * 32 + kq * 8]);
            float4 w1 = *(const float4*)(&wy[y * 32 + kq * 8 + 4]);
            gr0 += hv * w0.x; gi0 += hv * w0.y;
            gr1 += hv * w0.z; gi1 += hv * w0.w;
            gr2 += hv * w1.x; gi2 += hv * w1.y;
            gr3 += hv * w1.z; gi3 += hv * w1.w;
        }
        *(float4*)(&gt[xx][kq * 8])     = make_float4(gr0, gi0, gr1, gi1);
        *(float4*)(&gt[xx][kq * 8 + 4]) = make_float4(gr2, gi2, gr3, gi3);
    }
    __syncthreads();
    {
        int kxm = t & 31, kyq = t >> 5;
        float ar0 = 0.f, ai0 = 0.f, ar1 = 0.f, ai1 = 0.f;
#pragma unroll 4
        for (int xx = 0; xx < 64; ++xx) {
            float2 tw = *(const float2*)(&twx[xx * 64 + 2 * kxm]);
            float4 g = *(const float4*)(&gt[xx][kyq * 4]);
            ar0 += g.x * tw.x - g.y * tw.y;  ai0 += g.x * tw.y + g.y * tw.x;
            ar1 += g.z * tw.x - g.w * tw.y;  ai1 += g.z * tw.y + g.w * tw.x;
        }
        float* fb = F + (size_t)bid * 1024 + kxm * 32 + kyq * 4;
        *(float4*)(fb) = make_float4(ar0, ai0, ar1, ai1);
    }
}

// ---------------- spectral multiply v4: register double-buffered pipeline ----------------
__global__ __launch_bounds__(256, 2) void spectral_kernel(
    const float* __restrict__ F, float* __restrict__ FoA, float* __restrict__ FoB,
    const float* __restrict__ w1, const float* __restrict__ w2,
    const int* __restrict__ estart, int l)
{
    int e = blockIdx.x;
    int z = blockIdx.z;
    int wsel = z & 1, cih = z >> 1;
    int p0 = estart[e], ne = estart[e + 1] - p0;
    if (ne == 0) return;
    int t = threadIdx.x;
    int co = blockIdx.y * 4 + (t >> 6);
    int lane = t & 63;

    const float* wbase = (wsel == 0 ? w1 : w2) + (size_t)(e * 4 + l) * 2097152;
    const float* Wc = wbase + (size_t)(cih * 32) * 32768 + (size_t)co * 512 + lane * 8;
    const float* Fc0 = F + (size_t)p0 * 65536 + (size_t)(cih * 32) * 1024 + wsel * 512 + lane * 8;
    float* Fob = (cih ? FoB : FoA) + (size_t)p0 * 65536 + (size_t)co * 1024 + wsel * 512 + lane * 8;

    for (int pc = 0; pc < ne; pc += 8) {
        int np = ne - pc; if (np > 8) np = 8;
        float4 a0[8], a1[8];
#pragma unroll
        for (int p = 0; p < 8; ++p) {
            a0[p] = make_float4(0.f, 0.f, 0.f, 0.f);
            a1[p] = make_float4(0.f, 0.f, 0.f, 0.f);
        }
        const float* Wp = Wc;
        const float* Fp = Fc0 + (size_t)pc * 65536;
        float4 wa[2], wb[2], fa[2][8], fb[2][8];
        // prologue: buffer 0 <- ci = 0
        wa[0] = LD4(Wp); wb[0] = LD4(Wp + 4);
#pragma unroll
        for (int p = 0; p < 8; ++p) {
            fa[0][p] = LD4(Fp + (size_t)p * 65536);
            fb[0][p] = LD4(Fp + (size_t)p * 65536 + 4);
        }
#pragma unroll
        for (int ci = 0; ci < 32; ++ci) {
            const int cur = ci & 1, nx = cur ^ 1;
            const float* Wn = Wp + 32768;
            const float* Fn = Fp + 1024;
            if (ci < 31) {  // static under full unroll
                wa[nx] = LD4(Wn); wb[nx] = LD4(Wn + 4);
#pragma unroll
                for (int p = 0; p < 8; ++p) {
                    fa[nx][p] = LD4(Fn + (size_t)p * 65536);
                    fb[nx][p] = LD4(Fn + (size_t)p * 65536 + 4);
                }
            }
            float4 w_a = wa[cur], w_b = wb[cur];
#pragma unroll
            for (int p = 0; p < 8; ++p) {
                float4 f_a = fa[cur][p], f_b = fb[cur][p];
                a0[p].x += f_a.x * w_a.x - f_a.y * w_a.y;
                a0[p].y += f_a.x * w_a.y + f_a.y * w_a.x;
                a0[p].z += f_a.z * w_a.z - f_a.w * w_a.w;
                a0[p].w += f_a.z * w_a.w + f_a.w * w_a.z;
                a1[p].x += f_b.x * w_b.x - f_b.y * w_b.y;
                a1[p].y += f_b.x * w_b.y + f_b.y * w_b.x;
                a1[p].z += f_b.z * w_b.z - f_b.w * w_b.w;
                a1[p].w += f_b.z * w_b.w + f_b.w * w_b.z;
            }
            Wp = Wn; Fp = Fn;
        }
#pragma unroll
        for (int p = 0; p < 8; ++p) {
            if (p < np) {
                float* d = Fob + (size_t)(pc + p) * 65536;
                *(float4*)(d) = a0[p];
                *(float4*)(d + 4) = a1[p];
            }
        }
    }
}

// ---------------- 1x1 conv (skip / proj1) ----------------
__global__ __launch_bounds__(256) void conv1x1_kernel(
    const float* __restrict__ src, float* __restrict__ dst,
    const float* __restrict__ Wall, const float* __restrict__ Ball,
    const int* __restrict__ pair_e, int wmul, int wadd, int do_gelu)
{
    int p = blockIdx.x, tile = blockIdx.y, t = threadIdx.x;
    int e = pair_e[p];
    int widx = e * wmul + wadd;
    const float* W = Wall + (size_t)widx * 4096;
    const float* B = Ball + widx * 64;
    const float* s = src + (size_t)p * 262144 + tile * 256 + t;
    float acc[64];
#pragma unroll
    for (int c = 0; c < 64; ++c) acc[c] = 0.f;
    for (int ci = 0; ci < 64; ++ci) {
        float hv = s[(size_t)ci * 4096];
        const float* wr = W + ci * 64;
#pragma unroll
        for (int c = 0; c < 64; ++c) acc[c] += hv * wr[c];
    }
    float* d = dst + (size_t)p * 262144 + tile * 256 + t;
    for (int c = 0; c < 64; ++c) {
        float v = acc[c] + B[c];
        if (do_gelu) v = gelu_f(v);
        d[(size_t)c * 4096] = v;
    }
}

// ---------------- inverse DFT + skip-add + gelu, 4 (p,co) items per block ----------------
__global__ __launch_bounds__(256) void inv_kernel(
    const float* __restrict__ FoA, const float* __restrict__ FoB,
    const float* __restrict__ WY2, float* __restrict__ dst_h, int do_gelu)
{
    __shared__ float wy2[2048];
    __shared__ float twl[128];
    __shared__ float fo_s[1024];
    __shared__ float tT[64][36];
    __shared__ float ot[64][66];
    int t = threadIdx.x;
    for (int i = t; i < 512; i += 256) *(float4*)(&wy2[i * 4]) = *(const float4*)(WY2 + i * 4);
    if (t < 64) {
        float a = TWOPI_F * (float)t / 64.f;
        twl[2 * t] = cosf(a);
        twl[2 * t + 1] = sinf(a);
    }
    __syncthreads();

    for (int item = 0; item < 4; ++item) {
        int wid = blockIdx.x * 4 + item;
        int p = wid >> 6, co = wid & 63;
        const float* fA = FoA + (size_t)p * 65536 + (size_t)co * 1024;
        const float* fB = FoB + (size_t)p * 65536 + (size_t)co * 1024;
        {
            float4 a = *(const float4*)(fA + t * 4);
            float4 b = *(const float4*)(fB + t * 4);
            *(float4*)(&fo_s[t * 4]) = make_float4(a.x + b.x, a.y + b.y, a.z + b.z, a.w + b.w);
        }
        __syncthreads();
        {
            int xx = t & 63, kq = t >> 6;
            float Tr0 = 0.f, Ti0 = 0.f, Tr1 = 0.f, Ti1 = 0.f;
            float Tr2 = 0.f, Ti2 = 0.f, Tr3 = 0.f, Ti3 = 0.f;
#pragma unroll 4
            for (int kxm = 0; kxm < 32; ++kxm) {
                int kx = kxm < 16 ? kxm : kxm + 32;
                int idx = (kx * xx) & 63;
                float c_ = twl[2 * idx], s_ = twl[2 * idx + 1];
                float4 f0 = *(const float4*)(&fo_s[kxm * 32 + kq * 8]);
                float4 f1 = *(const float4*)(&fo_s[kxm * 32 + kq * 8 + 4]);
                Tr0 += f0.x * c_ - f0.y * s_;  Ti0 += f0.x * s_ + f0.y * c_;
                Tr1 += f0.z * c_ - f0.w * s_;  Ti1 += f0.z * s_ + f0.w * c_;
                Tr2 += f1.x * c_ - f1.y * s_;  Ti2 += f1.x * s_ + f1.y * c_;
                Tr3 += f1.z * c_ - f1.w * s_;  Ti3 += f1.z * s_ + f1.w * c_;
            }
            *(float4*)(&tT[xx][kq * 8])     = make_float4(Tr0, Ti0, Tr1, Ti1);
            *(float4*)(&tT[xx][kq * 8 + 4]) = make_float4(Tr2, Ti2, Tr3, Ti3);
        }
        __syncthreads();
        {
            int xx = t & 63, yq = t >> 6;
            float Trr[16], Tii[16];
#pragma unroll
            for (int q = 0; q < 8; ++q) {
                float4 v = *(const float4*)(&tT[xx][q * 4]);
                Trr[q * 2] = v.x; Tii[q * 2] = v.y;
                Trr[q * 2 + 1] = v.z; Tii[q * 2 + 1] = v.w;
            }
            for (int j = 0; j < 16; ++j) {
                int y = yq * 16 + j;
                const float* wr = &wy2[y * 32];
                float acc = 0.f;
#pragma unroll
                for (int k = 0; k < 16; ++k)
                    acc += Trr[k] * wr[2 * k] - Tii[k] * wr[2 * k + 1];
                ot[xx][y] = acc;
            }
        }
        __syncthreads();
        {
            float* base = dst_h + (size_t)p * 262144 + (size_t)co * 4096;
            for (int r = 0; r < 16; ++r) {
                int gidx = r * 256 + t;
                int xx = gidx >> 6, y = gidx & 63;
                float v = base[gidx] + ot[xx][y];
                if (do_gelu) v = gelu_f(v);
                base[gidx] = v;
            }
        }
        __syncthreads();
    }
}

// ---------------- proj2 + weighted accumulate ----------------
__global__ __launch_bounds__(256) void proj2_kernel(
    const float* __restrict__ hsrc, const float* __restrict__ p2w, const float* __restrict__ p2b,
    const int* __restrict__ pair_b, const int* __restrict__ pair_e,
    const float* __restrict__ pw, float* __restrict__ out)
{
    int p = blockIdx.x, tile = blockIdx.y, t = threadIdx.x;
    int b = pair_b[p], e = pair_e[p];
    float wgt = pw[p];
    const float* h = hsrc + (size_t)p * 262144 + tile * 256 + t;
    const float* w2 = p2w + e * 64;
    float acc = p2b[e];
#pragma unroll
    for (int c = 0; c < 64; ++c) acc += h[(size_t)c * 4096] * w2[c];
    atomicAdd(out + (size_t)b * 4096 + tile * 256 + t, wgt * acc);
}

// ---------------- launch ----------------
extern "C" void kernel_launch(void* const* d_in, const int* in_sizes, int n_in,
                              void* d_out, int out_size, void* d_ws, size_t ws_size,
                              hipStream_t stream) {
    const float* x    = (const float*)d_in[0];
    const float* encw = (const float*)d_in[1];
    const float* encb = (const float*)d_in[2];
    const float* wqkv = (const float*)d_in[3];
    const float* bqkv = (const float*)d_in[4];
    const float* wo   = (const float*)d_in[5];
    const float* bo   = (const float*)d_in[6];
    const float* ln1g = (const float*)d_in[7];
    const float* ln1b = (const float*)d_in[8];
    const float* fw1  = (const float*)d_in[9];
    const float* fb1  = (const float*)d_in[10];
    const float* fw2  = (const float*)d_in[11];
    const float* fb2  = (const float*)d_in[12];
    const float* ln2g = (const float*)d_in[13];
    const float* ln2b = (const float*)d_in[14];
    const float* fcw  = (const float*)d_in[15];
    const float* fcb  = (const float*)d_in[16];
    const float* lw   = (const float*)d_in[17];
    const float* lb   = (const float*)d_in[18];
    const float* sw1  = (const float*)d_in[19];
    const float* sw2  = (const float*)d_in[20];
    const float* skw  = (const float*)d_in[21];
    const float* skb  = (const float*)d_in[22];
    const float* p1w  = (const float*)d_in[23];
    const float* p1b  = (const float*)d_in[24];
    const float* p2w  = (const float*)d_in[25];
    const float* p2b  = (const float*)d_in[26];
    float* out = (float*)d_out;

    float* wsf    = (float*)d_ws;
    float* rw     = wsf;               // 256
    float* pair_w = wsf + 256;         // 64
    int*   ipart  = (int*)(wsf + 320);
    int* pair_b = ipart;               // 64
    int* pair_e = ipart + 64;          // 64
    int* estart = ipart + 128;         // 9
    float* Wy  = wsf + 512;            // 2048
    float* TWX = wsf + 2560;           // 4096
    float* WY2 = wsf + 6656;           // 2048
    float* hA  = wsf + 16384;                       // 64 * 262144
    float* hB  = hA + (size_t)64 * 262144;          // 64 * 262144
    float* F   = hB + (size_t)64 * 262144;          // 64 * 65536
    float* FoA = F + (size_t)64 * 65536;            // 64 * 65536
    float* FoB = FoA + (size_t)64 * 65536;          // 64 * 65536
    size_t need = (16384 + 2ull * 64 * 262144 + 64ull * 65536 + 64ull * 131072) * 4;
    if (ws_size < need) return;

    hipMemsetAsync(d_out, 0, (size_t)out_size * sizeof(float), stream);
    init_tables_kernel<<<1, 256, 0, stream>>>(Wy, TWX, WY2);
    router_kernel<<<32, 512, 0, stream>>>(x, encw, encb, wqkv, bqkv, wo, bo, ln1g, ln1b,
                                          fw1, fb1, fw2, fb2, ln2g, ln2b, fcw, fcb, rw);
    build_pairs_kernel<<<1, 64, 0, stream>>>(rw, pair_b, pair_e, pair_w, estart);
    lift_kernel<<<dim3(64, 16), 256, 0, stream>>>(x, lw, lb, pair_b, pair_e, hA);
    for (int l = 0; l < 4; ++l) {
        float* cur = (l & 1) ? hB : hA;
        float* nxt = (l & 1) ? hA : hB;
        fwdft_kernel<<<4096, 256, 0, stream>>>(cur, Wy, TWX, F);
        spectral_kernel<<<dim3(8, 16, 4), 256, 0, stream>>>(F, FoA, FoB, sw1, sw2, estart, l);
        conv1x1_kernel<<<dim3(64, 16), 256, 0, stream>>>(cur, nxt, skw, skb, pair_e, 4, l, 0);
        inv_kernel<<<1024, 256, 0, stream>>>(FoA, FoB, WY2, nxt, (l < 3) ? 1 : 0);
    }
    conv1x1_kernel<<<dim3(64, 16), 256, 0, stream>>>(hA, hB, p1w, p1b, pair_e, 1, 0, 1);
    proj2_kernel<<<dim3(64, 16), 256, 0, stream>>>(hB, p2w, p2b, pair_b, pair_e, pair_w, out);
}

// Round 7
// 2296.528 us; speedup vs baseline: 4.1650x; 4.1650x over previous
//
#include <hip/hip_runtime.h>
#include <math.h>

#define TWOPI_F 6.283185307179586f
#define LD4(p) (*(const float4*)(p))

__device__ __forceinline__ float gelu_f(float v) {
    float u = 0.7978845608028654f * (v + 0.044715f * v * v * v);
    return 0.5f * v * (1.f + tanhf(u));
}

// ---------------- twiddle tables ----------------
__global__ void init_tables_kernel(float* __restrict__ Wy, float* __restrict__ TWX,
                                   float* __restrict__ WY2) {
    int t = threadIdx.x;
    for (int i = t; i < 1024; i += 256) {
        int y = i >> 4, k = i & 15;
        int m = (k * y) & 63;
        float a = -TWOPI_F * (float)m / 64.f;
        Wy[y * 32 + 2 * k]     = cosf(a);
        Wy[y * 32 + 2 * k + 1] = sinf(a);
    }
    for (int i = t; i < 2048; i += 256) {
        int x = i >> 5, kxm = i & 31;
        int kx = kxm < 16 ? kxm : kxm + 32;
        int m = (kx * x) & 63;
        float a = -TWOPI_F * (float)m / 64.f;
        TWX[x * 64 + 2 * kxm]     = cosf(a);
        TWX[x * 64 + 2 * kxm + 1] = sinf(a);
    }
    for (int i = t; i < 1024; i += 256) {
        int y = i >> 4, k = i & 15;
        int m = (k * y) & 63;
        float a = TWOPI_F * (float)m / 64.f;
        float sc = (k == 0 ? 1.f : 2.f) / 4096.f;
        WY2[y * 32 + 2 * k]     = sc * cosf(a);
        WY2[y * 32 + 2 * k + 1] = sc * sinf(a);
    }
}

// ---------------- router v3: weight-reuse layout (col-group x row-group) ----------------
__global__ __launch_bounds__(512) void router_kernel(
    const float* __restrict__ x, const float* __restrict__ enc_w, const float* __restrict__ enc_b,
    const float* __restrict__ wqkv, const float* __restrict__ bqkv,
    const float* __restrict__ wo, const float* __restrict__ bo,
    const float* __restrict__ ln1g, const float* __restrict__ ln1b,
    const float* __restrict__ w1, const float* __restrict__ b1,
    const float* __restrict__ w2, const float* __restrict__ b2,
    const float* __restrict__ ln2g, const float* __restrict__ ln2b,
    const float* __restrict__ fcw, const float* __restrict__ fcb,
    float* __restrict__ rw)
{
    __shared__ float s[64][65];
    __shared__ float qk[64][193];
    __shared__ float sc[64][65];
    __shared__ float o64[64][65];
    __shared__ float feat[64];
    __shared__ float logits[8];
    int b = blockIdx.x, t = threadIdx.x;

    for (int i = t; i < 4096; i += 512) {
        int w_ = i >> 6, d = i & 63;
        s[w_][d] = x[b * 4096 + w_] * enc_w[d] + enc_b[d];
    }
    __syncthreads();

    for (int l = 0; l < 2; ++l) {
        // ---- QKV: 48 col4-groups x 8 row-groups (384 active threads, 8 rows each)
        {
            const float* Wq = wqkv + l * 64 * 192;
            const float* Bq = bqkv + l * 192;
            int c4 = t % 48, rg = t / 48;
            if (rg < 8) {
                const float* wcol = Wq + 4 * c4;
                float4 bq = LD4(Bq + 4 * c4);
                float4 acc[8];
#pragma unroll
                for (int i = 0; i < 8; ++i) acc[i] = bq;
                int r0 = rg * 8;
#pragma unroll 8
                for (int k = 0; k < 64; ++k) {
                    float4 wv = LD4(wcol + k * 192);
#pragma unroll
                    for (int i = 0; i < 8; ++i) {
                        float sv = s[r0 + i][k];
                        acc[i].x += sv * wv.x; acc[i].y += sv * wv.y;
                        acc[i].z += sv * wv.z; acc[i].w += sv * wv.w;
                    }
                }
#pragma unroll
                for (int i = 0; i < 8; ++i) {
                    qk[r0 + i][4 * c4]     = acc[i].x;
                    qk[r0 + i][4 * c4 + 1] = acc[i].y;
                    qk[r0 + i][4 * c4 + 2] = acc[i].z;
                    qk[r0 + i][4 * c4 + 3] = acc[i].w;
                }
            }
        }
        __syncthreads();
        // ---- attention heads
        for (int h = 0; h < 4; ++h) {
            for (int i = t; i < 4096; i += 512) {
                int q = i >> 6, kj = i & 63;
                float acc = 0.f;
#pragma unroll
                for (int d = 0; d < 16; ++d)
                    acc += qk[q][h * 16 + d] * qk[kj][64 + h * 16 + d];
                sc[q][kj] = acc * 0.25f;
            }
            __syncthreads();
            if (t < 64) {
                float m = -1e30f;
                for (int j = 0; j < 64; ++j) m = fmaxf(m, sc[t][j]);
                float sum = 0.f;
                for (int j = 0; j < 64; ++j) { float e2 = expf(sc[t][j] - m); sc[t][j] = e2; sum += e2; }
                float inv = 1.f / sum;
                for (int j = 0; j < 64; ++j) sc[t][j] *= inv;
            }
            __syncthreads();
            for (int i = t; i < 1024; i += 512) {
                int q = i >> 4, d = i & 15;
                float acc = 0.f;
#pragma unroll 8
                for (int j = 0; j < 64; ++j) acc += sc[q][j] * qk[j][128 + h * 16 + d];
                o64[q][h * 16 + d] = acc;
            }
            __syncthreads();
        }
        // ---- attn out proj + residual: 16 col4 x 32 rg (2 rows each)
        {
            const float* Wo = wo + l * 4096;
            const float* Bo = bo + l * 64;
            int c4 = t & 15, rg = t >> 4;
            const float* wcol = Wo + 4 * c4;
            float4 acc0 = LD4(Bo + 4 * c4), acc1 = acc0;
            int r0 = rg * 2;
#pragma unroll 8
            for (int k = 0; k < 64; ++k) {
                float4 wv = LD4(wcol + k * 64);
                float h0 = o64[r0][k], h1 = o64[r0 + 1][k];
                acc0.x += h0 * wv.x; acc0.y += h0 * wv.y;
                acc0.z += h0 * wv.z; acc0.w += h0 * wv.w;
                acc1.x += h1 * wv.x; acc1.y += h1 * wv.y;
                acc1.z += h1 * wv.z; acc1.w += h1 * wv.w;
            }
            sc[r0][4 * c4]     = s[r0][4 * c4]     + acc0.x;
            sc[r0][4 * c4 + 1] = s[r0][4 * c4 + 1] + acc0.y;
            sc[r0][4 * c4 + 2] = s[r0][4 * c4 + 2] + acc0.z;
            sc[r0][4 * c4 + 3] = s[r0][4 * c4 + 3] + acc0.w;
            sc[r0 + 1][4 * c4]     = s[r0 + 1][4 * c4]     + acc1.x;
            sc[r0 + 1][4 * c4 + 1] = s[r0 + 1][4 * c4 + 1] + acc1.y;
            sc[r0 + 1][4 * c4 + 2] = s[r0 + 1][4 * c4 + 2] + acc1.z;
            sc[r0 + 1][4 * c4 + 3] = s[r0 + 1][4 * c4 + 3] + acc1.w;
        }
        __syncthreads();
        if (t < 64) {  // LN1: sc -> s
            float m = 0.f;
            for (int j = 0; j < 64; ++j) m += sc[t][j];
            m *= (1.f / 64.f);
            float v = 0.f;
            for (int j = 0; j < 64; ++j) { float d = sc[t][j] - m; v += d * d; }
            v *= (1.f / 64.f);
            float inv = rsqrtf(v + 1e-5f);
            for (int j = 0; j < 64; ++j)
                s[t][j] = (sc[t][j] - m) * inv * ln1g[l * 64 + j] + ln1b[l * 64 + j];
        }
        __syncthreads();
        // ---- FFN1 + relu: 64 col4 x 8 rg (8 rows each); out split qk/o64
        {
            const float* W1 = w1 + l * 64 * 256;
            const float* B1 = b1 + l * 256;
            int c4 = t & 63, rg = t >> 6;
            const float* wcol = W1 + 4 * c4;
            float4 b1v = LD4(B1 + 4 * c4);
            float4 acc[8];
#pragma unroll
            for (int i = 0; i < 8; ++i) acc[i] = b1v;
            int r0 = rg * 8;
#pragma unroll 4
            for (int k = 0; k < 64; ++k) {
                float4 wv = LD4(wcol + k * 256);
#pragma unroll
                for (int i = 0; i < 8; ++i) {
                    float sv = s[r0 + i][k];
                    acc[i].x += sv * wv.x; acc[i].y += sv * wv.y;
                    acc[i].z += sv * wv.z; acc[i].w += sv * wv.w;
                }
            }
#pragma unroll
            for (int i = 0; i < 8; ++i) {
                float a0 = fmaxf(acc[i].x, 0.f), a1 = fmaxf(acc[i].y, 0.f);
                float a2 = fmaxf(acc[i].z, 0.f), a3 = fmaxf(acc[i].w, 0.f);
                if (c4 < 48) {
                    qk[r0 + i][4 * c4] = a0; qk[r0 + i][4 * c4 + 1] = a1;
                    qk[r0 + i][4 * c4 + 2] = a2; qk[r0 + i][4 * c4 + 3] = a3;
                } else {
                    int c = 4 * c4 - 192;
                    o64[r0 + i][c] = a0; o64[r0 + i][c + 1] = a1;
                    o64[r0 + i][c + 2] = a2; o64[r0 + i][c + 3] = a3;
                }
            }
        }
        __syncthreads();
        // ---- FFN2 + residual: 16 col4 x 32 rg (2 rows each), K=256
        {
            const float* W2 = w2 + l * 256 * 64;
            const float* B2 = b2 + l * 64;
            int c4 = t & 15, rg = t >> 4;
            const float* wcol = W2 + 4 * c4;
            float4 acc0 = LD4(B2 + 4 * c4), acc1 = acc0;
            int r0 = rg * 2;
#pragma unroll 8
            for (int k = 0; k < 192; ++k) {
                float4 wv = LD4(wcol + k * 64);
                float h0 = qk[r0][k], h1 = qk[r0 + 1][k];
                acc0.x += h0 * wv.x; acc0.y += h0 * wv.y;
                acc0.z += h0 * wv.z; acc0.w += h0 * wv.w;
                acc1.x += h1 * wv.x; acc1.y += h1 * wv.y;
                acc1.z += h1 * wv.z; acc1.w += h1 * wv.w;
            }
#pragma unroll 8
            for (int k = 192; k < 256; ++k) {
                float4 wv = LD4(wcol + k * 64);
                float h0 = o64[r0][k - 192], h1 = o64[r0 + 1][k - 192];
                acc0.x += h0 * wv.x; acc0.y += h0 * wv.y;
                acc0.z += h0 * wv.z; acc0.w += h0 * wv.w;
                acc1.x += h1 * wv.x; acc1.y += h1 * wv.y;
                acc1.z += h1 * wv.z; acc1.w += h1 * wv.w;
            }
            sc[r0][4 * c4]     = s[r0][4 * c4]     + acc0.x;
            sc[r0][4 * c4 + 1] = s[r0][4 * c4 + 1] + acc0.y;
            sc[r0][4 * c4 + 2] = s[r0][4 * c4 + 2] + acc0.z;
            sc[r0][4 * c4 + 3] = s[r0][4 * c4 + 3] + acc0.w;
            sc[r0 + 1][4 * c4]     = s[r0 + 1][4 * c4]     + acc1.x;
            sc[r0 + 1][4 * c4 + 1] = s[r0 + 1][4 * c4 + 1] + acc1.y;
            sc[r0 + 1][4 * c4 + 2] = s[r0 + 1][4 * c4 + 2] + acc1.z;
            sc[r0 + 1][4 * c4 + 3] = s[r0 + 1][4 * c4 + 3] + acc1.w;
        }
        __syncthreads();
        if (t < 64) {  // LN2: sc -> s
            float m = 0.f;
            for (int j = 0; j < 64; ++j) m += sc[t][j];
            m *= (1.f / 64.f);
            float v = 0.f;
            for (int j = 0; j < 64; ++j) { float d = sc[t][j] - m; v += d * d; }
            v *= (1.f / 64.f);
            float inv = rsqrtf(v + 1e-5f);
            for (int j = 0; j < 64; ++j)
                s[t][j] = (sc[t][j] - m) * inv * ln2g[l * 64 + j] + ln2b[l * 64 + j];
        }
        __syncthreads();
    }
    if (t < 64) {
        float m = -1e30f;
        for (int r = 0; r < 64; ++r) m = fmaxf(m, s[r][t]);
        feat[t] = m;
    }
    __syncthreads();
    if (t < 8) {
        float acc = fcb[t];
        for (int k = 0; k < 64; ++k) acc += feat[k] * fcw[k * 8 + t];
        logits[t] = acc;
    }
    __syncthreads();
    if (t == 0) {
        int i0 = 0;
        for (int j = 1; j < 8; ++j) if (logits[j] > logits[i0]) i0 = j;
        int i1 = -1;
        for (int j = 0; j < 8; ++j) {
            if (j == i0) continue;
            if (i1 < 0 || logits[j] > logits[i1]) i1 = j;
        }
        float e1 = expf(logits[i1] - logits[i0]);
        float w0 = 1.f / (1.f + e1);
        float w1v = e1 / (1.f + e1);
        for (int j = 0; j < 8; ++j) rw[b * 8 + j] = 0.f;
        rw[b * 8 + i0] = w0;
        rw[b * 8 + i1] = w1v;
    }
}

// ---------------- build compact (b,e) pair list grouped by expert ----------------
__global__ void build_pairs_kernel(const float* __restrict__ rw, int* __restrict__ pair_b,
                                   int* __restrict__ pair_e, float* __restrict__ pair_w,
                                   int* __restrict__ estart) {
    __shared__ float r[256];
    __shared__ int cnt[8], off[9];
    int t = threadIdx.x;
    for (int i = t; i < 256; i += 64) r[i] = rw[i];
    if (t < 64) { pair_b[t] = 0; pair_e[t] = 0; pair_w[t] = 0.f; }
    __syncthreads();
    if (t < 8) {
        int c = 0;
        for (int b = 0; b < 32; ++b) if (r[b * 8 + t] != 0.f) ++c;
        cnt[t] = c;
    }
    __syncthreads();
    if (t == 0) {
        int a = 0;
        for (int e = 0; e < 8; ++e) { off[e] = a; a += cnt[e]; }
        off[8] = a;
        for (int e = 0; e <= 8; ++e) estart[e] = off[e];
    }
    __syncthreads();
    if (t < 8) {
        int n = off[t];
        for (int b = 0; b < 32; ++b) {
            float w = r[b * 8 + t];
            if (w != 0.f) { pair_b[n] = b; pair_e[n] = t; pair_w[n] = w; ++n; }
        }
    }
}

// ---------------- lift ----------------
__global__ __launch_bounds__(256) void lift_kernel(const float* __restrict__ x,
    const float* __restrict__ lw, const float* __restrict__ lb,
    const int* __restrict__ pair_b, const int* __restrict__ pair_e, float* __restrict__ hA) {
    int p = blockIdx.x, tile = blockIdx.y, t = threadIdx.x;
    int b = pair_b[p], e = pair_e[p];
    float* h = hA + (size_t)p * 262144;
    const float* xb = x + (size_t)b * 4096;
    for (int i = tile * 16384 + t; i < (tile + 1) * 16384; i += 256) {
        int co = i >> 12, xy = i & 4095;
        h[i] = xb[xy] * lw[e * 64 + co] + lb[e * 64 + co];
    }
}

// ---------------- fused forward DFT (y then x), one block per (p,ci) ----------------
__global__ __launch_bounds__(256) void fwdft_kernel(const float* __restrict__ h,
    const float* __restrict__ Wy, const float* __restrict__ TWX, float* __restrict__ F) {
    __shared__ float ht[64][68];
    __shared__ float gt[64][36];
    __shared__ float wy[2048];
    __shared__ float twx[4096];
    int bid = blockIdx.x;
    int t = threadIdx.x;
    const float* src = h + (size_t)bid * 4096;
    for (int i = t; i < 1024; i += 256) {
        float4 v = *(const float4*)(src + i * 4);
        int x = (i * 4) >> 6, y = (i * 4) & 63;
        *(float4*)(&ht[x][y]) = v;
    }
    for (int i = t; i < 512; i += 256) *(float4*)(&wy[i * 4]) = *(const float4*)(Wy + i * 4);
    for (int i = t; i < 1024; i += 256) *(float4*)(&twx[i * 4]) = *(const float4*)(TWX + i * 4);
    __syncthreads();
    {
        int xx = t >> 2, kq = t & 3;
        float gr0 = 0.f, gi0 = 0.f, gr1 = 0.f, gi1 = 0.f;
        float gr2 = 0.f, gi2 = 0.f, gr3 = 0.f, gi3 = 0.f;
#pragma unroll 4
        for (int y = 0; y < 64; ++y) {
            float hv = ht[xx][y];
            float4 w0 = *(const float4*)(&wy[y * 32 + kq * 8]);
            float4 w1 = *(const float4*)(&wy[y * 32 + kq * 8 + 4]);
            gr0 += hv * w0.x; gi0 += hv * w0.y;
            gr1 += hv * w0.z; gi1 += hv * w0.w;
            gr2 += hv * w1.x; gi2 += hv * w1.y;
            gr3 += hv * w1.z; gi3 += hv * w1.w;
        }
        *(float4*)(&gt[xx][kq * 8])     = make_float4(gr0, gi0, gr1, gi1);
        *(float4*)(&gt[xx][kq * 8 + 4]) = make_float4(gr2, gi2, gr3, gi3);
    }
    __syncthreads();
    {
        int kxm = t & 31, kyq = t >> 5;
        float ar0 = 0.f, ai0 = 0.f, ar1 = 0.f, ai1 = 0.f;
#pragma unroll 4
        for (int xx = 0; xx < 64; ++xx) {
            float2 tw = *(const float2*)(&twx[xx * 64 + 2 * kxm]);
            float4 g = *(const float4*)(&gt[xx][kyq * 4]);
            ar0 += g.x * tw.x - g.y * tw.y;  ai0 += g.x * tw.y + g.y * tw.x;
            ar1 += g.z * tw.x - g.w * tw.y;  ai1 += g.z * tw.y + g.w * tw.x;
        }
        float* fb = F + (size_t)bid * 1024 + kxm * 32 + kyq * 4;
        *(float4*)(fb) = make_float4(ar0, ai0, ar1, ai1);
    }
}

// ---------------- spectral multiply v5: fine split (1 float4 x 8p per thread) ----------------
// grid (8 e, 16 co-groups, 8 = mq x cih x wsel), block = 4 waves (one co each).
// Thread owns float4 at mode-offset mq*256 + lane*4 of the 512-float (ci,co,wsel)
// chunk. Wave reads 1KB contiguous for both W and F -> coalesced. acc = 32 VGPR.
__global__ __launch_bounds__(256) void spectral_kernel(
    const float* __restrict__ F, float* __restrict__ FoA, float* __restrict__ FoB,
    const float* __restrict__ w1, const float* __restrict__ w2,
    const int* __restrict__ estart, int l)
{
    int e = blockIdx.x;
    int z = blockIdx.z;                       // bit0 = wsel, bit1 = cih, bit2 = mq
    int wsel = z & 1, cih = (z >> 1) & 1, mq = z >> 2;
    int p0 = estart[e], ne = estart[e + 1] - p0;
    if (ne == 0) return;
    int t = threadIdx.x;
    int co = blockIdx.y * 4 + (t >> 6);
    int lane = t & 63;
    int moff = mq * 256 + lane * 4;           // float offset within 512-float chunk

    const float* wbase = (wsel == 0 ? w1 : w2) + (size_t)(e * 4 + l) * 2097152;
    const float* Wc  = wbase + (size_t)(cih * 32) * 32768 + (size_t)co * 512 + moff;
    const float* Fc0 = F + (size_t)p0 * 65536 + (size_t)(cih * 32) * 1024 + wsel * 512 + moff;
    float* Fob = (cih ? FoB : FoA) + (size_t)p0 * 65536 + (size_t)co * 1024 + wsel * 512 + moff;

    for (int pc = 0; pc < ne; pc += 8) {
        int np = ne - pc; if (np > 8) np = 8;
        float4 acc[8];
#pragma unroll
        for (int p = 0; p < 8; ++p) acc[p] = make_float4(0.f, 0.f, 0.f, 0.f);
        const float* Wp = Wc;
        const float* Fp = Fc0 + (size_t)pc * 65536;
        for (int ci = 0; ci < 32; ++ci) {
            float4 wv = LD4(Wp);
#pragma unroll
            for (int p = 0; p < 8; ++p) {
                // p >= np reads in-workspace garbage (never stored) - static indexing
                float4 fv = LD4(Fp + (size_t)p * 65536);
                acc[p].x += fv.x * wv.x - fv.y * wv.y;
                acc[p].y += fv.x * wv.y + fv.y * wv.x;
                acc[p].z += fv.z * wv.z - fv.w * wv.w;
                acc[p].w += fv.z * wv.w + fv.w * wv.z;
            }
            Wp += 32768;
            Fp += 1024;
        }
#pragma unroll
        for (int p = 0; p < 8; ++p) {
            if (p < np)
                *(float4*)(Fob + (size_t)(pc + p) * 65536) = acc[p];
        }
    }
}

// ---------------- 1x1 conv (skip / proj1) ----------------
__global__ __launch_bounds__(256) void conv1x1_kernel(
    const float* __restrict__ src, float* __restrict__ dst,
    const float* __restrict__ Wall, const float* __restrict__ Ball,
    const int* __restrict__ pair_e, int wmul, int wadd, int do_gelu)
{
    int p = blockIdx.x, tile = blockIdx.y, t = threadIdx.x;
    int e = pair_e[p];
    int widx = e * wmul + wadd;
    const float* W = Wall + (size_t)widx * 4096;
    const float* B = Ball + widx * 64;
    const float* s = src + (size_t)p * 262144 + tile * 256 + t;
    float acc[64];
#pragma unroll
    for (int c = 0; c < 64; ++c) acc[c] = 0.f;
    for (int ci = 0; ci < 64; ++ci) {
        float hv = s[(size_t)ci * 4096];
        const float* wr = W + ci * 64;
#pragma unroll
        for (int c = 0; c < 64; ++c) acc[c] += hv * wr[c];
    }
    float* d = dst + (size_t)p * 262144 + tile * 256 + t;
    for (int c = 0; c < 64; ++c) {
        float v = acc[c] + B[c];
        if (do_gelu) v = gelu_f(v);
        d[(size_t)c * 4096] = v;
    }
}

// ---------------- inverse DFT + skip-add + gelu, 4 (p,co) items per block ----------------
__global__ __launch_bounds__(256) void inv_kernel(
    const float* __restrict__ FoA, const float* __restrict__ FoB,
    const float* __restrict__ WY2, float* __restrict__ dst_h, int do_gelu)
{
    __shared__ float wy2[2048];
    __shared__ float twl[128];
    __shared__ float fo_s[1024];
    __shared__ float tT[64][36];
    __shared__ float ot[64][66];
    int t = threadIdx.x;
    for (int i = t; i < 512; i += 256) *(float4*)(&wy2[i * 4]) = *(const float4*)(WY2 + i * 4);
    if (t < 64) {
        float a = TWOPI_F * (float)t / 64.f;
        twl[2 * t] = cosf(a);
        twl[2 * t + 1] = sinf(a);
    }
    __syncthreads();

    for (int item = 0; item < 4; ++item) {
        int wid = blockIdx.x * 4 + item;
        int p = wid >> 6, co = wid & 63;
        const float* fA = FoA + (size_t)p * 65536 + (size_t)co * 1024;
        const float* fB = FoB + (size_t)p * 65536 + (size_t)co * 1024;
        {
            float4 a = *(const float4*)(fA + t * 4);
            float4 b = *(const float4*)(fB + t * 4);
            *(float4*)(&fo_s[t * 4]) = make_float4(a.x + b.x, a.y + b.y, a.z + b.z, a.w + b.w);
        }
        __syncthreads();
        {
            int xx = t & 63, kq = t >> 6;
            float Tr0 = 0.f, Ti0 = 0.f, Tr1 = 0.f, Ti1 = 0.f;
            float Tr2 = 0.f, Ti2 = 0.f, Tr3 = 0.f, Ti3 = 0.f;
#pragma unroll 4
            for (int kxm = 0; kxm < 32; ++kxm) {
                int kx = kxm < 16 ? kxm : kxm + 32;
                int idx = (kx * xx) & 63;
                float c_ = twl[2 * idx], s_ = twl[2 * idx + 1];
                float4 f0 = *(const float4*)(&fo_s[kxm * 32 + kq * 8]);
                float4 f1 = *(const float4*)(&fo_s[kxm * 32 + kq * 8 + 4]);
                Tr0 += f0.x * c_ - f0.y * s_;  Ti0 += f0.x * s_ + f0.y * c_;
                Tr1 += f0.z * c_ - f0.w * s_;  Ti1 += f0.z * s_ + f0.w * c_;
                Tr2 += f1.x * c_ - f1.y * s_;  Ti2 += f1.x * s_ + f1.y * c_;
                Tr3 += f1.z * c_ - f1.w * s_;  Ti3 += f1.z * s_ + f1.w * c_;
            }
            *(float4*)(&tT[xx][kq * 8])     = make_float4(Tr0, Ti0, Tr1, Ti1);
            *(float4*)(&tT[xx][kq * 8 + 4]) = make_float4(Tr2, Ti2, Tr3, Ti3);
        }
        __syncthreads();
        {
            int xx = t & 63, yq = t >> 6;
            float Trr[16], Tii[16];
#pragma unroll
            for (int q = 0; q < 8; ++q) {
                float4 v = *(const float4*)(&tT[xx][q * 4]);
                Trr[q * 2] = v.x; Tii[q * 2] = v.y;
                Trr[q * 2 + 1] = v.z; Tii[q * 2 + 1] = v.w;
            }
            for (int j = 0; j < 16; ++j) {
                int y = yq * 16 + j;
                const float* wr = &wy2[y * 32];
                float acc = 0.f;
#pragma unroll
                for (int k = 0; k < 16; ++k)
                    acc += Trr[k] * wr[2 * k] - Tii[k] * wr[2 * k + 1];
                ot[xx][y] = acc;
            }
        }
        __syncthreads();
        {
            float* base = dst_h + (size_t)p * 262144 + (size_t)co * 4096;
            for (int r = 0; r < 16; ++r) {
                int gidx = r * 256 + t;
                int xx = gidx >> 6, y = gidx & 63;
                float v = base[gidx] + ot[xx][y];
                if (do_gelu) v = gelu_f(v);
                base[gidx] = v;
            }
        }
        __syncthreads();
    }
}

// ---------------- proj2 + weighted accumulate ----------------
__global__ __launch_bounds__(256) void proj2_kernel(
    const float* __restrict__ hsrc, const float* __restrict__ p2w, const float* __restrict__ p2b,
    const int* __restrict__ pair_b, const int* __restrict__ pair_e,
    const float* __restrict__ pw, float* __restrict__ out)
{
    int p = blockIdx.x, tile = blockIdx.y, t = threadIdx.x;
    int b = pair_b[p], e = pair_e[p];
    float wgt = pw[p];
    const float* h = hsrc + (size_t)p * 262144 + tile * 256 + t;
    const float* w2 = p2w + e * 64;
    float acc = p2b[e];
#pragma unroll
    for (int c = 0; c < 64; ++c) acc += h[(size_t)c * 4096] * w2[c];
    atomicAdd(out + (size_t)b * 4096 + tile * 256 + t, wgt * acc);
}

// ---------------- launch ----------------
extern "C" void kernel_launch(void* const* d_in, const int* in_sizes, int n_in,
                              void* d_out, int out_size, void* d_ws, size_t ws_size,
                              hipStream_t stream) {
    const float* x    = (const float*)d_in[0];
    const float* encw = (const float*)d_in[1];
    const float* encb = (const float*)d_in[2];
    const float* wqkv = (const float*)d_in[3];
    const float* bqkv = (const float*)d_in[4];
    const float* wo   = (const float*)d_in[5];
    const float* bo   = (const float*)d_in[6];
    const float* ln1g = (const float*)d_in[7];
    const float* ln1b = (const float*)d_in[8];
    const float* fw1  = (const float*)d_in[9];
    const float* fb1  = (const float*)d_in[10];
    const float* fw2  = (const float*)d_in[11];
    const float* fb2  = (const float*)d_in[12];
    const float* ln2g = (const float*)d_in[13];
    const float* ln2b = (const float*)d_in[14];
    const float* fcw  = (const float*)d_in[15];
    const float* fcb  = (const float*)d_in[16];
    const float* lw   = (const float*)d_in[17];
    const float* lb   = (const float*)d_in[18];
    const float* sw1  = (const float*)d_in[19];
    const float* sw2  = (const float*)d_in[20];
    const float* skw  = (const float*)d_in[21];
    const float* skb  = (const float*)d_in[22];
    const float* p1w  = (const float*)d_in[23];
    const float* p1b  = (const float*)d_in[24];
    const float* p2w  = (const float*)d_in[25];
    const float* p2b  = (const float*)d_in[26];
    float* out = (float*)d_out;

    float* wsf    = (float*)d_ws;
    float* rw     = wsf;               // 256
    float* pair_w = wsf + 256;         // 64
    int*   ipart  = (int*)(wsf + 320);
    int* pair_b = ipart;               // 64
    int* pair_e = ipart + 64;          // 64
    int* estart = ipart + 128;         // 9
    float* Wy  = wsf + 512;            // 2048
    float* TWX = wsf + 2560;           // 4096
    float* WY2 = wsf + 6656;           // 2048
    float* hA  = wsf + 16384;                       // 64 * 262144
    float* hB  = hA + (size_t)64 * 262144;          // 64 * 262144
    float* F   = hB + (size_t)64 * 262144;          // 64 * 65536
    float* FoA = F + (size_t)64 * 65536;            // 64 * 65536
    float* FoB = FoA + (size_t)64 * 65536;          // 64 * 65536
    size_t need = (16384 + 2ull * 64 * 262144 + 64ull * 65536 + 64ull * 131072) * 4;
    if (ws_size < need) return;

    hipMemsetAsync(d_out, 0, (size_t)out_size * sizeof(float), stream);
    init_tables_kernel<<<1, 256, 0, stream>>>(Wy, TWX, WY2);
    router_kernel<<<32, 512, 0, stream>>>(x, encw, encb, wqkv, bqkv, wo, bo, ln1g, ln1b,
                                          fw1, fb1, fw2, fb2, ln2g, ln2b, fcw, fcb, rw);
    build_pairs_kernel<<<1, 64, 0, stream>>>(rw, pair_b, pair_e, pair_w, estart);
    lift_kernel<<<dim3(64, 16), 256, 0, stream>>>(x, lw, lb, pair_b, pair_e, hA);
    for (int l = 0; l < 4; ++l) {
        float* cur = (l & 1) ? hB : hA;
        float* nxt = (l & 1) ? hA : hB;
        fwdft_kernel<<<4096, 256, 0, stream>>>(cur, Wy, TWX, F);
        spectral_kernel<<<dim3(8, 16, 8), 256, 0, stream>>>(F, FoA, FoB, sw1, sw2, estart, l);
        conv1x1_kernel<<<dim3(64, 16), 256, 0, stream>>>(cur, nxt, skw, skb, pair_e, 4, l, 0);
        inv_kernel<<<1024, 256, 0, stream>>>(FoA, FoB, WY2, nxt, (l < 3) ? 1 : 0);
    }
    conv1x1_kernel<<<dim3(64, 16), 256, 0, stream>>>(hA, hB, p1w, p1b, pair_e, 1, 0, 1);
    proj2_kernel<<<dim3(64, 16), 256, 0, stream>>>(hB, p2w, p2b, pair_b, pair_e, pair_w, out);
}

// Round 8
// 2283.615 us; speedup vs baseline: 4.1885x; 1.0057x over previous
//
#include <hip/hip_runtime.h>
#include <math.h>

#define TWOPI_F 6.283185307179586f
#define LD4(p) (*(const float4*)(p))

__device__ __forceinline__ float gelu_f(float v) {
    float u = 0.7978845608028654f * (v + 0.044715f * v * v * v);
    return 0.5f * v * (1.f + tanhf(u));
}

// ---------------- twiddle tables ----------------
__global__ void init_tables_kernel(float* __restrict__ Wy, float* __restrict__ TWX,
                                   float* __restrict__ WY2) {
    int t = threadIdx.x;
    for (int i = t; i < 1024; i += 256) {
        int y = i >> 4, k = i & 15;
        int m = (k * y) & 63;
        float a = -TWOPI_F * (float)m / 64.f;
        Wy[y * 32 + 2 * k]     = cosf(a);
        Wy[y * 32 + 2 * k + 1] = sinf(a);
    }
    for (int i = t; i < 2048; i += 256) {
        int x = i >> 5, kxm = i & 31;
        int kx = kxm < 16 ? kxm : kxm + 32;
        int m = (kx * x) & 63;
        float a = -TWOPI_F * (float)m / 64.f;
        TWX[x * 64 + 2 * kxm]     = cosf(a);
        TWX[x * 64 + 2 * kxm + 1] = sinf(a);
    }
    for (int i = t; i < 1024; i += 256) {
        int y = i >> 4, k = i & 15;
        int m = (k * y) & 63;
        float a = TWOPI_F * (float)m / 64.f;
        float sc = (k == 0 ? 1.f : 2.f) / 4096.f;
        WY2[y * 32 + 2 * k]     = sc * cosf(a);
        WY2[y * 32 + 2 * k + 1] = sc * sinf(a);
    }
}

// ---------------- router v3: weight-reuse layout (col-group x row-group) ----------------
__global__ __launch_bounds__(512) void router_kernel(
    const float* __restrict__ x, const float* __restrict__ enc_w, const float* __restrict__ enc_b,
    const float* __restrict__ wqkv, const float* __restrict__ bqkv,
    const float* __restrict__ wo, const float* __restrict__ bo,
    const float* __restrict__ ln1g, const float* __restrict__ ln1b,
    const float* __restrict__ w1, const float* __restrict__ b1,
    const float* __restrict__ w2, const float* __restrict__ b2,
    const float* __restrict__ ln2g, const float* __restrict__ ln2b,
    const float* __restrict__ fcw, const float* __restrict__ fcb,
    float* __restrict__ rw)
{
    __shared__ float s[64][65];
    __shared__ float qk[64][193];
    __shared__ float sc[64][65];
    __shared__ float o64[64][65];
    __shared__ float feat[64];
    __shared__ float logits[8];
    int b = blockIdx.x, t = threadIdx.x;

    for (int i = t; i < 4096; i += 512) {
        int w_ = i >> 6, d = i & 63;
        s[w_][d] = x[b * 4096 + w_] * enc_w[d] + enc_b[d];
    }
    __syncthreads();

    for (int l = 0; l < 2; ++l) {
        // ---- QKV: 48 col4-groups x 8 row-groups (384 active threads, 8 rows each)
        {
            const float* Wq = wqkv + l * 64 * 192;
            const float* Bq = bqkv + l * 192;
            int c4 = t % 48, rg = t / 48;
            if (rg < 8) {
                const float* wcol = Wq + 4 * c4;
                float4 bq = LD4(Bq + 4 * c4);
                float4 acc[8];
#pragma unroll
                for (int i = 0; i < 8; ++i) acc[i] = bq;
                int r0 = rg * 8;
#pragma unroll 8
                for (int k = 0; k < 64; ++k) {
                    float4 wv = LD4(wcol + k * 192);
#pragma unroll
                    for (int i = 0; i < 8; ++i) {
                        float sv = s[r0 + i][k];
                        acc[i].x += sv * wv.x; acc[i].y += sv * wv.y;
                        acc[i].z += sv * wv.z; acc[i].w += sv * wv.w;
                    }
                }
#pragma unroll
                for (int i = 0; i < 8; ++i) {
                    qk[r0 + i][4 * c4]     = acc[i].x;
                    qk[r0 + i][4 * c4 + 1] = acc[i].y;
                    qk[r0 + i][4 * c4 + 2] = acc[i].z;
                    qk[r0 + i][4 * c4 + 3] = acc[i].w;
                }
            }
        }
        __syncthreads();
        // ---- attention heads
        for (int h = 0; h < 4; ++h) {
            for (int i = t; i < 4096; i += 512) {
                int q = i >> 6, kj = i & 63;
                float acc = 0.f;
#pragma unroll
                for (int d = 0; d < 16; ++d)
                    acc += qk[q][h * 16 + d] * qk[kj][64 + h * 16 + d];
                sc[q][kj] = acc * 0.25f;
            }
            __syncthreads();
            if (t < 64) {
                float m = -1e30f;
                for (int j = 0; j < 64; ++j) m = fmaxf(m, sc[t][j]);
                float sum = 0.f;
                for (int j = 0; j < 64; ++j) { float e2 = expf(sc[t][j] - m); sc[t][j] = e2; sum += e2; }
                float inv = 1.f / sum;
                for (int j = 0; j < 64; ++j) sc[t][j] *= inv;
            }
            __syncthreads();
            for (int i = t; i < 1024; i += 512) {
                int q = i >> 4, d = i & 15;
                float acc = 0.f;
#pragma unroll 8
                for (int j = 0; j < 64; ++j) acc += sc[q][j] * qk[j][128 + h * 16 + d];
                o64[q][h * 16 + d] = acc;
            }
            __syncthreads();
        }
        // ---- attn out proj + residual: 16 col4 x 32 rg (2 rows each)
        {
            const float* Wo = wo + l * 4096;
            const float* Bo = bo + l * 64;
            int c4 = t & 15, rg = t >> 4;
            const float* wcol = Wo + 4 * c4;
            float4 acc0 = LD4(Bo + 4 * c4), acc1 = acc0;
            int r0 = rg * 2;
#pragma unroll 8
            for (int k = 0; k < 64; ++k) {
                float4 wv = LD4(wcol + k * 64);
                float h0 = o64[r0][k], h1 = o64[r0 + 1][k];
                acc0.x += h0 * wv.x; acc0.y += h0 * wv.y;
                acc0.z += h0 * wv.z; acc0.w += h0 * wv.w;
                acc1.x += h1 * wv.x; acc1.y += h1 * wv.y;
                acc1.z += h1 * wv.z; acc1.w += h1 * wv.w;
            }
            sc[r0][4 * c4]     = s[r0][4 * c4]     + acc0.x;
            sc[r0][4 * c4 + 1] = s[r0][4 * c4 + 1] + acc0.y;
            sc[r0][4 * c4 + 2] = s[r0][4 * c4 + 2] + acc0.z;
            sc[r0][4 * c4 + 3] = s[r0][4 * c4 + 3] + acc0.w;
            sc[r0 + 1][4 * c4]     = s[r0 + 1][4 * c4]     + acc1.x;
            sc[r0 + 1][4 * c4 + 1] = s[r0 + 1][4 * c4 + 1] + acc1.y;
            sc[r0 + 1][4 * c4 + 2] = s[r0 + 1][4 * c4 + 2] + acc1.z;
            sc[r0 + 1][4 * c4 + 3] = s[r0 + 1][4 * c4 + 3] + acc1.w;
        }
        __syncthreads();
        if (t < 64) {  // LN1: sc -> s
            float m = 0.f;
            for (int j = 0; j < 64; ++j) m += sc[t][j];
            m *= (1.f / 64.f);
            float v = 0.f;
            for (int j = 0; j < 64; ++j) { float d = sc[t][j] - m; v += d * d; }
            v *= (1.f / 64.f);
            float inv = rsqrtf(v + 1e-5f);
            for (int j = 0; j < 64; ++j)
                s[t][j] = (sc[t][j] - m) * inv * ln1g[l * 64 + j] + ln1b[l * 64 + j];
        }
        __syncthreads();
        // ---- FFN1 + relu: 64 col4 x 8 rg (8 rows each); out split qk/o64
        {
            const float* W1 = w1 + l * 64 * 256;
            const float* B1 = b1 + l * 256;
            int c4 = t & 63, rg = t >> 6;
            const float* wcol = W1 + 4 * c4;
            float4 b1v = LD4(B1 + 4 * c4);
            float4 acc[8];
#pragma unroll
            for (int i = 0; i < 8; ++i) acc[i] = b1v;
            int r0 = rg * 8;
#pragma unroll 4
            for (int k = 0; k < 64; ++k) {
                float4 wv = LD4(wcol + k * 256);
#pragma unroll
                for (int i = 0; i < 8; ++i) {
                    float sv = s[r0 + i][k];
                    acc[i].x += sv * wv.x; acc[i].y += sv * wv.y;
                    acc[i].z += sv * wv.z; acc[i].w += sv * wv.w;
                }
            }
#pragma unroll
            for (int i = 0; i < 8; ++i) {
                float a0 = fmaxf(acc[i].x, 0.f), a1 = fmaxf(acc[i].y, 0.f);
                float a2 = fmaxf(acc[i].z, 0.f), a3 = fmaxf(acc[i].w, 0.f);
                if (c4 < 48) {
                    qk[r0 + i][4 * c4] = a0; qk[r0 + i][4 * c4 + 1] = a1;
                    qk[r0 + i][4 * c4 + 2] = a2; qk[r0 + i][4 * c4 + 3] = a3;
                } else {
                    int c = 4 * c4 - 192;
                    o64[r0 + i][c] = a0; o64[r0 + i][c + 1] = a1;
                    o64[r0 + i][c + 2] = a2; o64[r0 + i][c + 3] = a3;
                }
            }
        }
        __syncthreads();
        // ---- FFN2 + residual: 16 col4 x 32 rg (2 rows each), K=256
        {
            const float* W2 = w2 + l * 256 * 64;
            const float* B2 = b2 + l * 64;
            int c4 = t & 15, rg = t >> 4;
            const float* wcol = W2 + 4 * c4;
            float4 acc0 = LD4(B2 + 4 * c4), acc1 = acc0;
            int r0 = rg * 2;
#pragma unroll 8
            for (int k = 0; k < 192; ++k) {
                float4 wv = LD4(wcol + k * 64);
                float h0 = qk[r0][k], h1 = qk[r0 + 1][k];
                acc0.x += h0 * wv.x; acc0.y += h0 * wv.y;
                acc0.z += h0 * wv.z; acc0.w += h0 * wv.w;
                acc1.x += h1 * wv.x; acc1.y += h1 * wv.y;
                acc1.z += h1 * wv.z; acc1.w += h1 * wv.w;
            }
#pragma unroll 8
            for (int k = 192; k < 256; ++k) {
                float4 wv = LD4(wcol + k * 64);
                float h0 = o64[r0][k - 192], h1 = o64[r0 + 1][k - 192];
                acc0.x += h0 * wv.x; acc0.y += h0 * wv.y;
                acc0.z += h0 * wv.z; acc0.w += h0 * wv.w;
                acc1.x += h1 * wv.x; acc1.y += h1 * wv.y;
                acc1.z += h1 * wv.z; acc1.w += h1 * wv.w;
            }
            sc[r0][4 * c4]     = s[r0][4 * c4]     + acc0.x;
            sc[r0][4 * c4 + 1] = s[r0][4 * c4 + 1] + acc0.y;
            sc[r0][4 * c4 + 2] = s[r0][4 * c4 + 2] + acc0.z;
            sc[r0][4 * c4 + 3] = s[r0][4 * c4 + 3] + acc0.w;
            sc[r0 + 1][4 * c4]     = s[r0 + 1][4 * c4]     + acc1.x;
            sc[r0 + 1][4 * c4 + 1] = s[r0 + 1][4 * c4 + 1] + acc1.y;
            sc[r0 + 1][4 * c4 + 2] = s[r0 + 1][4 * c4 + 2] + acc1.z;
            sc[r0 + 1][4 * c4 + 3] = s[r0 + 1][4 * c4 + 3] + acc1.w;
        }
        __syncthreads();
        if (t < 64) {  // LN2: sc -> s
            float m = 0.f;
            for (int j = 0; j < 64; ++j) m += sc[t][j];
            m *= (1.f / 64.f);
            float v = 0.f;
            for (int j = 0; j < 64; ++j) { float d = sc[t][j] - m; v += d * d; }
            v *= (1.f / 64.f);
            float inv = rsqrtf(v + 1e-5f);
            for (int j = 0; j < 64; ++j)
                s[t][j] = (sc[t][j] - m) * inv * ln2g[l * 64 + j] + ln2b[l * 64 + j];
        }
        __syncthreads();
    }
    if (t < 64) {
        float m = -1e30f;
        for (int r = 0; r < 64; ++r) m = fmaxf(m, s[r][t]);
        feat[t] = m;
    }
    __syncthreads();
    if (t < 8) {
        float acc = fcb[t];
        for (int k = 0; k < 64; ++k) acc += feat[k] * fcw[k * 8 + t];
        logits[t] = acc;
    }
    __syncthreads();
    if (t == 0) {
        int i0 = 0;
        for (int j = 1; j < 8; ++j) if (logits[j] > logits[i0]) i0 = j;
        int i1 = -1;
        for (int j = 0; j < 8; ++j) {
            if (j == i0) continue;
            if (i1 < 0 || logits[j] > logits[i1]) i1 = j;
        }
        float e1 = expf(logits[i1] - logits[i0]);
        float w0 = 1.f / (1.f + e1);
        float w1v = e1 / (1.f + e1);
        for (int j = 0; j < 8; ++j) rw[b * 8 + j] = 0.f;
        rw[b * 8 + i0] = w0;
        rw[b * 8 + i1] = w1v;
    }
}

// ---------------- build compact (b,e) pair list grouped by expert ----------------
__global__ void build_pairs_kernel(const float* __restrict__ rw, int* __restrict__ pair_b,
                                   int* __restrict__ pair_e, float* __restrict__ pair_w,
                                   int* __restrict__ estart) {
    __shared__ float r[256];
    __shared__ int cnt[8], off[9];
    int t = threadIdx.x;
    for (int i = t; i < 256; i += 64) r[i] = rw[i];
    if (t < 64) { pair_b[t] = 0; pair_e[t] = 0; pair_w[t] = 0.f; }
    __syncthreads();
    if (t < 8) {
        int c = 0;
        for (int b = 0; b < 32; ++b) if (r[b * 8 + t] != 0.f) ++c;
        cnt[t] = c;
    }
    __syncthreads();
    if (t == 0) {
        int a = 0;
        for (int e = 0; e < 8; ++e) { off[e] = a; a += cnt[e]; }
        off[8] = a;
        for (int e = 0; e <= 8; ++e) estart[e] = off[e];
    }
    __syncthreads();
    if (t < 8) {
        int n = off[t];
        for (int b = 0; b < 32; ++b) {
            float w = r[b * 8 + t];
            if (w != 0.f) { pair_b[n] = b; pair_e[n] = t; pair_w[n] = w; ++n; }
        }
    }
}

// ---------------- lift ----------------
__global__ __launch_bounds__(256) void lift_kernel(const float* __restrict__ x,
    const float* __restrict__ lw, const float* __restrict__ lb,
    const int* __restrict__ pair_b, const int* __restrict__ pair_e, float* __restrict__ hA) {
    int p = blockIdx.x, tile = blockIdx.y, t = threadIdx.x;
    int b = pair_b[p], e = pair_e[p];
    float* h = hA + (size_t)p * 262144;
    const float* xb = x + (size_t)b * 4096;
    for (int i = tile * 16384 + t; i < (tile + 1) * 16384; i += 256) {
        int co = i >> 12, xy = i & 4095;
        h[i] = xb[xy] * lw[e * 64 + co] + lb[e * 64 + co];
    }
}

// ---------------- fused forward DFT (y then x), one block per (p,ci) ----------------
__global__ __launch_bounds__(256) void fwdft_kernel(const float* __restrict__ h,
    const float* __restrict__ Wy, const float* __restrict__ TWX, float* __restrict__ F) {
    __shared__ float ht[64][68];
    __shared__ float gt[64][36];
    __shared__ float wy[2048];
    __shared__ float twx[4096];
    int bid = blockIdx.x;
    int t = threadIdx.x;
    const float* src = h + (size_t)bid * 4096;
    for (int i = t; i < 1024; i += 256) {
        float4 v = *(const float4*)(src + i * 4);
        int x = (i * 4) >> 6, y = (i * 4) & 63;
        *(float4*)(&ht[x][y]) = v;
    }
    for (int i = t; i < 512; i += 256) *(float4*)(&wy[i * 4]) = *(const float4*)(Wy + i * 4);
    for (int i = t; i < 1024; i += 256) *(float4*)(&twx[i * 4]) = *(const float4*)(TWX + i * 4);
    __syncthreads();
    {
        int xx = t >> 2, kq = t & 3;
        float gr0 = 0.f, gi0 = 0.f, gr1 = 0.f, gi1 = 0.f;
        float gr2 = 0.f, gi2 = 0.f, gr3 = 0.f, gi3 = 0.f;
#pragma unroll 4
        for (int y = 0; y < 64; ++y) {
            float hv = ht[xx][y];
            float4 w0 = *(const float4*)(&wy[y * 32 + kq * 8]);
            float4 w1 = *(const float4*)(&wy[y * 32 + kq * 8 + 4]);
            gr0 += hv * w0.x; gi0 += hv * w0.y;
            gr1 += hv * w0.z; gi1 += hv * w0.w;
            gr2 += hv * w1.x; gi2 += hv * w1.y;
            gr3 += hv * w1.z; gi3 += hv * w1.w;
        }
        *(float4*)(&gt[xx][kq * 8])     = make_float4(gr0, gi0, gr1, gi1);
        *(float4*)(&gt[xx][kq * 8 + 4]) = make_float4(gr2, gi2, gr3, gi3);
    }
    __syncthreads();
    {
        int kxm = t & 31, kyq = t >> 5;
        float ar0 = 0.f, ai0 = 0.f, ar1 = 0.f, ai1 = 0.f;
#pragma unroll 4
        for (int xx = 0; xx < 64; ++xx) {
            float2 tw = *(const float2*)(&twx[xx * 64 + 2 * kxm]);
            float4 g = *(const float4*)(&gt[xx][kyq * 4]);
            ar0 += g.x * tw.x - g.y * tw.y;  ai0 += g.x * tw.y + g.y * tw.x;
            ar1 += g.z * tw.x - g.w * tw.y;  ai1 += g.z * tw.y + g.w * tw.x;
        }
        float* fb = F + (size_t)bid * 1024 + kxm * 32 + kyq * 4;
        *(float4*)(fb) = make_float4(ar0, ai0, ar1, ai1);
    }
}

// ---------------- spectral multiply v6: 2 co per thread (F amortization) ----------------
// grid (8 e, 8 co-groups, 8 = mq x cih x wsel), block = 4 waves; wave owns co pair.
// Per ci: 2 coalesced W float4 loads + 8 F float4 loads shared by both co.
// F L2-traffic: 8 co-group redundancy x 16MB = 128MB (vs 1GB at 1 co/thread).
__global__ __launch_bounds__(256, 2) void spectral_kernel(
    const float* __restrict__ F, float* __restrict__ FoA, float* __restrict__ FoB,
    const float* __restrict__ w1, const float* __restrict__ w2,
    const int* __restrict__ estart, int l)
{
    int e = blockIdx.x;
    int z = blockIdx.z;                       // bit0 = wsel, bit1 = cih, bit2 = mq
    int wsel = z & 1, cih = (z >> 1) & 1, mq = z >> 2;
    int p0 = estart[e], ne = estart[e + 1] - p0;
    if (ne == 0) return;
    int t = threadIdx.x;
    int co0 = blockIdx.y * 8 + (t >> 6) * 2;  // wave's first co; second is co0+1
    int lane = t & 63;
    int moff = mq * 256 + lane * 4;           // float offset within 512-float chunk

    const float* wbase = (wsel == 0 ? w1 : w2) + (size_t)(e * 4 + l) * 2097152;
    const float* Wc  = wbase + (size_t)(cih * 32) * 32768 + (size_t)co0 * 512 + moff;
    const float* Fc0 = F + (size_t)p0 * 65536 + (size_t)(cih * 32) * 1024 + wsel * 512 + moff;
    float* Fob = (cih ? FoB : FoA) + (size_t)p0 * 65536 + (size_t)co0 * 1024 + wsel * 512 + moff;

    for (int pc = 0; pc < ne; pc += 8) {
        int np = ne - pc; if (np > 8) np = 8;
        float4 a0[8], a1[8];
#pragma unroll
        for (int p = 0; p < 8; ++p) {
            a0[p] = make_float4(0.f, 0.f, 0.f, 0.f);
            a1[p] = make_float4(0.f, 0.f, 0.f, 0.f);
        }
        const float* Wp = Wc;
        const float* Fp = Fc0 + (size_t)pc * 65536;
        for (int ci = 0; ci < 32; ++ci) {
            float4 w0 = LD4(Wp);
            float4 w1v = LD4(Wp + 512);
#pragma unroll
            for (int p = 0; p < 8; ++p) {
                // p >= np reads workspace garbage (never stored) - static indexing
                float4 fv = LD4(Fp + (size_t)p * 65536);
                a0[p].x += fv.x * w0.x - fv.y * w0.y;
                a0[p].y += fv.x * w0.y + fv.y * w0.x;
                a0[p].z += fv.z * w0.z - fv.w * w0.w;
                a0[p].w += fv.z * w0.w + fv.w * w0.z;
                a1[p].x += fv.x * w1v.x - fv.y * w1v.y;
                a1[p].y += fv.x * w1v.y + fv.y * w1v.x;
                a1[p].z += fv.z * w1v.z - fv.w * w1v.w;
                a1[p].w += fv.z * w1v.w + fv.w * w1v.z;
            }
            Wp += 32768;
            Fp += 1024;
        }
#pragma unroll
        for (int p = 0; p < 8; ++p) {
            if (p < np) {
                *(float4*)(Fob + (size_t)(pc + p) * 65536) = a0[p];
                *(float4*)(Fob + (size_t)(pc + p) * 65536 + 1024) = a1[p];
            }
        }
    }
}

// ---------------- 1x1 conv (skip / proj1) ----------------
__global__ __launch_bounds__(256) void conv1x1_kernel(
    const float* __restrict__ src, float* __restrict__ dst,
    const float* __restrict__ Wall, const float* __restrict__ Ball,
    const int* __restrict__ pair_e, int wmul, int wadd, int do_gelu)
{
    int p = blockIdx.x, tile = blockIdx.y, t = threadIdx.x;
    int e = pair_e[p];
    int widx = e * wmul + wadd;
    const float* W = Wall + (size_t)widx * 4096;
    const float* B = Ball + widx * 64;
    const float* s = src + (size_t)p * 262144 + tile * 256 + t;
    float acc[64];
#pragma unroll
    for (int c = 0; c < 64; ++c) acc[c] = 0.f;
    for (int ci = 0; ci < 64; ++ci) {
        float hv = s[(size_t)ci * 4096];
        const float* wr = W + ci * 64;
#pragma unroll
        for (int c = 0; c < 64; ++c) acc[c] += hv * wr[c];
    }
    float* d = dst + (size_t)p * 262144 + tile * 256 + t;
    for (int c = 0; c < 64; ++c) {
        float v = acc[c] + B[c];
        if (do_gelu) v = gelu_f(v);
        d[(size_t)c * 4096] = v;
    }
}

// ---------------- inverse DFT + skip-add + gelu, 4 (p,co) items per block ----------------
__global__ __launch_bounds__(256) void inv_kernel(
    const float* __restrict__ FoA, const float* __restrict__ FoB,
    const float* __restrict__ WY2, float* __restrict__ dst_h, int do_gelu)
{
    __shared__ float wy2[2048];
    __shared__ float twl[128];
    __shared__ float fo_s[1024];
    __shared__ float tT[64][36];
    __shared__ float ot[64][66];
    int t = threadIdx.x;
    for (int i = t; i < 512; i += 256) *(float4*)(&wy2[i * 4]) = *(const float4*)(WY2 + i * 4);
    if (t < 64) {
        float a = TWOPI_F * (float)t / 64.f;
        twl[2 * t] = cosf(a);
        twl[2 * t + 1] = sinf(a);
    }
    __syncthreads();

    for (int item = 0; item < 4; ++item) {
        int wid = blockIdx.x * 4 + item;
        int p = wid >> 6, co = wid & 63;
        const float* fA = FoA + (size_t)p * 65536 + (size_t)co * 1024;
        const float* fB = FoB + (size_t)p * 65536 + (size_t)co * 1024;
        {
            float4 a = *(const float4*)(fA + t * 4);
            float4 b = *(const float4*)(fB + t * 4);
            *(float4*)(&fo_s[t * 4]) = make_float4(a.x + b.x, a.y + b.y, a.z + b.z, a.w + b.w);
        }
        __syncthreads();
        {
            int xx = t & 63, kq = t >> 6;
            float Tr0 = 0.f, Ti0 = 0.f, Tr1 = 0.f, Ti1 = 0.f;
            float Tr2 = 0.f, Ti2 = 0.f, Tr3 = 0.f, Ti3 = 0.f;
#pragma unroll 4
            for (int kxm = 0; kxm < 32; ++kxm) {
                int kx = kxm < 16 ? kxm : kxm + 32;
                int idx = (kx * xx) & 63;
                float c_ = twl[2 * idx], s_ = twl[2 * idx + 1];
                float4 f0 = *(const float4*)(&fo_s[kxm * 32 + kq * 8]);
                float4 f1 = *(const float4*)(&fo_s[kxm * 32 + kq * 8 + 4]);
                Tr0 += f0.x * c_ - f0.y * s_;  Ti0 += f0.x * s_ + f0.y * c_;
                Tr1 += f0.z * c_ - f0.w * s_;  Ti1 += f0.z * s_ + f0.w * c_;
                Tr2 += f1.x * c_ - f1.y * s_;  Ti2 += f1.x * s_ + f1.y * c_;
                Tr3 += f1.z * c_ - f1.w * s_;  Ti3 += f1.z * s_ + f1.w * c_;
            }
            *(float4*)(&tT[xx][kq * 8])     = make_float4(Tr0, Ti0, Tr1, Ti1);
            *(float4*)(&tT[xx][kq * 8 + 4]) = make_float4(Tr2, Ti2, Tr3, Ti3);
        }
        __syncthreads();
        {
            int xx = t & 63, yq = t >> 6;
            float Trr[16], Tii[16];
#pragma unroll
            for (int q = 0; q < 8; ++q) {
                float4 v = *(const float4*)(&tT[xx][q * 4]);
                Trr[q * 2] = v.x; Tii[q * 2] = v.y;
                Trr[q * 2 + 1] = v.z; Tii[q * 2 + 1] = v.w;
            }
            for (int j = 0; j < 16; ++j) {
                int y = yq * 16 + j;
                const float* wr = &wy2[y * 32];
                float acc = 0.f;
#pragma unroll
                for (int k = 0; k < 16; ++k)
                    acc += Trr[k] * wr[2 * k] - Tii[k] * wr[2 * k + 1];
                ot[xx][y] = acc;
            }
        }
        __syncthreads();
        {
            float* base = dst_h + (size_t)p * 262144 + (size_t)co * 4096;
            for (int r = 0; r < 16; ++r) {
                int gidx = r * 256 + t;
                int xx = gidx >> 6, y = gidx & 63;
                float v = base[gidx] + ot[xx][y];
                if (do_gelu) v = gelu_f(v);
                base[gidx] = v;
            }
        }
        __syncthreads();
    }
}

// ---------------- proj2 + weighted accumulate ----------------
__global__ __launch_bounds__(256) void proj2_kernel(
    const float* __restrict__ hsrc, const float* __restrict__ p2w, const float* __restrict__ p2b,
    const int* __restrict__ pair_b, const int* __restrict__ pair_e,
    const float* __restrict__ pw, float* __restrict__ out)
{
    int p = blockIdx.x, tile = blockIdx.y, t = threadIdx.x;
    int b = pair_b[p], e = pair_e[p];
    float wgt = pw[p];
    const float* h = hsrc + (size_t)p * 262144 + tile * 256 + t;
    const float* w2 = p2w + e * 64;
    float acc = p2b[e];
#pragma unroll
    for (int c = 0; c < 64; ++c) acc += h[(size_t)c * 4096] * w2[c];
    atomicAdd(out + (size_t)b * 4096 + tile * 256 + t, wgt * acc);
}

// ---------------- launch ----------------
extern "C" void kernel_launch(void* const* d_in, const int* in_sizes, int n_in,
                              void* d_out, int out_size, void* d_ws, size_t ws_size,
                              hipStream_t stream) {
    const float* x    = (const float*)d_in[0];
    const float* encw = (const float*)d_in[1];
    const float* encb = (const float*)d_in[2];
    const float* wqkv = (const float*)d_in[3];
    const float* bqkv = (const float*)d_in[4];
    const float* wo   = (const float*)d_in[5];
    const float* bo   = (const float*)d_in[6];
    const float* ln1g = (const float*)d_in[7];
    const float* ln1b = (const float*)d_in[8];
    const float* fw1  = (const float*)d_in[9];
    const float* fb1  = (const float*)d_in[10];
    const float* fw2  = (const float*)d_in[11];
    const float* fb2  = (const float*)d_in[12];
    const float* ln2g = (const float*)d_in[13];
    const float* ln2b = (const float*)d_in[14];
    const float* fcw  = (const float*)d_in[15];
    const float* fcb  = (const float*)d_in[16];
    const float* lw   = (const float*)d_in[17];
    const float* lb   = (const float*)d_in[18];
    const float* sw1  = (const float*)d_in[19];
    const float* sw2  = (const float*)d_in[20];
    const float* skw  = (const float*)d_in[21];
    const float* skb  = (const float*)d_in[22];
    const float* p1w  = (const float*)d_in[23];
    const float* p1b  = (const float*)d_in[24];
    const float* p2w  = (const float*)d_in[25];
    const float* p2b  = (const float*)d_in[26];
    float* out = (float*)d_out;

    float* wsf    = (float*)d_ws;
    float* rw     = wsf;               // 256
    float* pair_w = wsf + 256;         // 64
    int*   ipart  = (int*)(wsf + 320);
    int* pair_b = ipart;               // 64
    int* pair_e = ipart + 64;          // 64
    int* estart = ipart + 128;         // 9
    float* Wy  = wsf + 512;            // 2048
    float* TWX = wsf + 2560;           // 4096
    float* WY2 = wsf + 6656;           // 2048
    float* hA  = wsf + 16384;                       // 64 * 262144
    float* hB  = hA + (size_t)64 * 262144;          // 64 * 262144
    float* F   = hB + (size_t)64 * 262144;          // 64 * 65536
    float* FoA = F + (size_t)64 * 65536;            // 64 * 65536
    float* FoB = FoA + (size_t)64 * 65536;          // 64 * 65536
    size_t need = (16384 + 2ull * 64 * 262144 + 64ull * 65536 + 64ull * 131072) * 4;
    if (ws_size < need) return;

    hipMemsetAsync(d_out, 0, (size_t)out_size * sizeof(float), stream);
    init_tables_kernel<<<1, 256, 0, stream>>>(Wy, TWX, WY2);
    router_kernel<<<32, 512, 0, stream>>>(x, encw, encb, wqkv, bqkv, wo, bo, ln1g, ln1b,
                                          fw1, fb1, fw2, fb2, ln2g, ln2b, fcw, fcb, rw);
    build_pairs_kernel<<<1, 64, 0, stream>>>(rw, pair_b, pair_e, pair_w, estart);
    lift_kernel<<<dim3(64, 16), 256, 0, stream>>>(x, lw, lb, pair_b, pair_e, hA);
    for (int l = 0; l < 4; ++l) {
        float* cur = (l & 1) ? hB : hA;
        float* nxt = (l & 1) ? hA : hB;
        fwdft_kernel<<<4096, 256, 0, stream>>>(cur, Wy, TWX, F);
        spectral_kernel<<<dim3(8, 8, 8), 256, 0, stream>>>(F, FoA, FoB, sw1, sw2, estart, l);
        conv1x1_kernel<<<dim3(64, 16), 256, 0, stream>>>(cur, nxt, skw, skb, pair_e, 4, l, 0);
        inv_kernel<<<1024, 256, 0, stream>>>(FoA, FoB, WY2, nxt, (l < 3) ? 1 : 0);
    }
    conv1x1_kernel<<<dim3(64, 16), 256, 0, stream>>>(hA, hB, p1w, p1b, pair_e, 1, 0, 1);
    proj2_kernel<<<dim3(64, 16), 256, 0, stream>>>(hB, p2w, p2b, pair_b, pair_e, pair_w, out);
}